// Round 6
// baseline (363.034 us; speedup 1.0000x reference)
//
#include <hip/hip_runtime.h>
#include <hip/hip_bf16.h>

#define N_NODES 100000
#define N_EDGES 1600000
#define IN_FEA 128
#define HIDDEN 128
#define RANK 64

#define NBUCK 391          // ceil(N_NODES/256): bucket b = nodes [b*256, b*256+256)
#define C_BLOCKS 1024
#define EPB 1563           // ceil(N_EDGES / C_BLOCKS)
#define GEMM1_BLOCKS 3125  // N_NODES / 32

// ---------------- helpers ----------------

__device__ __forceinline__ void fma4(float4& a, float s, const float4& b) {
    a.x = fmaf(s, b.x, a.x);
    a.y = fmaf(s, b.y, a.y);
    a.z = fmaf(s, b.z, a.z);
    a.w = fmaf(s, b.w, a.w);
}

__device__ __forceinline__ unsigned short f2bf_rne(float f) {
    unsigned u = __float_as_uint(f);
    u += 0x7fffu + ((u >> 16) & 1u);
    return (unsigned short)(u >> 16);
}

__device__ __forceinline__ float bf2f(unsigned short s) {
    return __uint_as_float(((unsigned)s) << 16);
}

// ---------------- fused GEMM1 + bucket histogram ----------------
// blocks [0, GEMM1_BLOCKS): h_bf = bf16(x @ W), 32 nodes/block, W in LDS.
// blocks [GEMM1_BLOCKS, GEMM1_BLOCKS+C_BLOCKS): per-block bucket histogram.

__global__ __launch_bounds__(256) void gemm1_hist_kernel(const float* __restrict__ x,
                                                         const float* __restrict__ W,
                                                         unsigned short* __restrict__ hb,
                                                         const int* __restrict__ dst,
                                                         int* __restrict__ bhist,
                                                         int* __restrict__ blockhist) {
    __shared__ float Wl[IN_FEA * RANK];  // 32 KB (hist aliases first 1.6 KB)
    int t = threadIdx.x;

    if (blockIdx.x >= GEMM1_BLOCKS) {
        // ---- histogram part ----
        int* hist = (int*)Wl;
        int b = blockIdx.x - GEMM1_BLOCKS;
        for (int i = t; i < NBUCK; i += 256) hist[i] = 0;
        __syncthreads();
        int b0 = b * EPB;
        int b1 = min(b0 + EPB, N_EDGES);
        for (int e = b0 + t; e < b1; e += 256)
            atomicAdd(&hist[dst[e] >> 8], 1);
        __syncthreads();
        for (int i = t; i < NBUCK; i += 256) {
            int c = hist[i];
            blockhist[b * NBUCK + i] = c;
            if (c) atomicAdd(&bhist[i], c);
        }
        return;
    }

    // ---- gemm1 part ----
    for (int i = t; i < IN_FEA * RANK; i += 256) Wl[i] = W[i];
    __syncthreads();

    int wave = t >> 6, lane = t & 63;
    int node0 = blockIdx.x * 32 + wave * 8 + (lane >> 4) * 2;
    int r0 = (lane & 15) * 4;

    const float4* xa = (const float4*)(x + (long)node0 * IN_FEA);
    const float4* xb = (const float4*)(x + (long)(node0 + 1) * IN_FEA);
    float4 acca = {0.f, 0.f, 0.f, 0.f};
    float4 accb = {0.f, 0.f, 0.f, 0.f};
    for (int k4 = 0; k4 < IN_FEA / 4; ++k4) {
        float4 va = xa[k4];
        float4 vb = xb[k4];
        int kb = k4 * 4;
        float4 w0 = *(const float4*)&Wl[(kb + 0) * RANK + r0];
        float4 w1 = *(const float4*)&Wl[(kb + 1) * RANK + r0];
        float4 w2 = *(const float4*)&Wl[(kb + 2) * RANK + r0];
        float4 w3 = *(const float4*)&Wl[(kb + 3) * RANK + r0];
        fma4(acca, va.x, w0); fma4(accb, vb.x, w0);
        fma4(acca, va.y, w1); fma4(accb, vb.y, w1);
        fma4(acca, va.z, w2); fma4(accb, vb.z, w2);
        fma4(acca, va.w, w3); fma4(accb, vb.w, w3);
    }
    ushort4 oa, ob;
    oa.x = f2bf_rne(acca.x); oa.y = f2bf_rne(acca.y);
    oa.z = f2bf_rne(acca.z); oa.w = f2bf_rne(acca.w);
    ob.x = f2bf_rne(accb.x); ob.y = f2bf_rne(accb.y);
    ob.z = f2bf_rne(accb.z); ob.w = f2bf_rne(accb.w);
    *(ushort4*)(hb + node0 * RANK + r0) = oa;
    *(ushort4*)(hb + (node0 + 1) * RANK + r0) = ob;
}

// ---------------- CSR build (rest) ----------------

__global__ void bucket_scan_kernel(const int* __restrict__ bhist,
                                   int* __restrict__ bucket_offs,
                                   int* __restrict__ bucket_cursor,
                                   int* __restrict__ offs) {
    __shared__ int sd[512];
    int t = threadIdx.x;
    int v = (t < NBUCK) ? bhist[t] : 0;
    sd[t] = v;
    __syncthreads();
    for (int off = 1; off < 512; off <<= 1) {
        int a = 0;
        if (t >= off) a = sd[t - off];
        __syncthreads();
        sd[t] += a;
        __syncthreads();
    }
    if (t < NBUCK) {
        int excl = sd[t] - v;
        bucket_offs[t] = excl;
        bucket_cursor[t] = excl;
    }
    if (t == 0) {
        bucket_offs[NBUCK] = N_EDGES;
        offs[N_NODES] = N_EDGES;
    }
}

__global__ __launch_bounds__(256) void binscatter_kernel(const int* __restrict__ src,
                                                         const int* __restrict__ dst,
                                                         const int* __restrict__ blockhist,
                                                         int* __restrict__ bucket_cursor,
                                                         unsigned* __restrict__ pairs) {
    __shared__ int wbase[NBUCK];
    __shared__ int cur[NBUCK];
    int t = threadIdx.x;
    for (int i = t; i < NBUCK; i += 256) {
        int c = blockhist[blockIdx.x * NBUCK + i];
        wbase[i] = c ? atomicAdd(&bucket_cursor[i], c) : 0;
        cur[i] = 0;
    }
    __syncthreads();
    int b0 = blockIdx.x * EPB;
    int b1 = min(b0 + EPB, N_EDGES);
    for (int e = b0 + t; e < b1; e += 256) {
        int d = dst[e];
        int s = src[e];
        int bk = d >> 8;
        int lp = atomicAdd(&cur[bk], 1);
        pairs[wbase[bk] + lp] = ((unsigned)s << 8) | (unsigned)(d & 255);
    }
}

__global__ __launch_bounds__(256) void bucket_build_kernel(const unsigned* __restrict__ pairs,
                                                           const int* __restrict__ bucket_offs,
                                                           int* __restrict__ offs,
                                                           int* __restrict__ eidx) {
    __shared__ int dcnt[256];
    __shared__ int sd[256];
    __shared__ int cur[256];
    int b = blockIdx.x, t = threadIdx.x;
    int base = bucket_offs[b], end = bucket_offs[b + 1];
    dcnt[t] = 0;
    __syncthreads();
    for (int i = base + t; i < end; i += 256)
        atomicAdd(&dcnt[pairs[i] & 255u], 1);
    __syncthreads();
    int v = dcnt[t];
    sd[t] = v;
    __syncthreads();
    for (int off = 1; off < 256; off <<= 1) {
        int a = 0;
        if (t >= off) a = sd[t - off];
        __syncthreads();
        sd[t] += a;
        __syncthreads();
    }
    int excl = sd[t] - v;
    int node = b * 256 + t;
    if (node < N_NODES) offs[node] = base + excl;
    cur[t] = excl;
    __syncthreads();
    for (int i = base + t; i < end; i += 256) {
        unsigned r = pairs[i];
        int lp = atomicAdd(&cur[r & 255u], 1);
        eidx[base + lp] = (int)(r >> 8);
    }
}

// ---------------- fused aggregation + GEMM2 (LDS-lite) ----------------
// 256 threads = 4 waves; 4 nodes/wave (16 nodes/block). Grid = 6250.
// Phase 1: per-wave products for 4 nodes, lane = rank (bf16 h gather, 128 B/row).
// Phase 2: trans rows via 4 KB LDS broadcast; V rows read from global (L1-hot, 32 KB).

__global__ __launch_bounds__(256, 6) void agg_gemm_kernel(const unsigned short* __restrict__ hb,
                                                          const float* __restrict__ norm,
                                                          const float* __restrict__ V,
                                                          const int* __restrict__ offs,
                                                          const int* __restrict__ eidx,
                                                          float* __restrict__ out) {
    __shared__ float4 pls[256];         // 4 KB only -> high occupancy
    int t = threadIdx.x;
    int wave = t >> 6, lane = t & 63;
    int base = blockIdx.x * 16 + wave * 4;

    float p[4];
#pragma unroll
    for (int i = 0; i < 4; ++i) {
        int node = base + i;
        int beg = offs[node], end = offs[node + 1];
        float pp = 1.0f;
        for (int c = beg; c < end; c += 64) {
            int n = min(64, end - c);
            int sidx = (c + lane < end) ? eidx[c + lane] : 0;
            int j = 0;
            for (; j + 8 <= n; j += 8) {
                int s0 = __shfl(sidx, j + 0);
                int s1 = __shfl(sidx, j + 1);
                int s2 = __shfl(sidx, j + 2);
                int s3 = __shfl(sidx, j + 3);
                int s4 = __shfl(sidx, j + 4);
                int s5 = __shfl(sidx, j + 5);
                int s6 = __shfl(sidx, j + 6);
                int s7 = __shfl(sidx, j + 7);
                float a0 = bf2f(hb[s0 * RANK + lane]);
                float a1 = bf2f(hb[s1 * RANK + lane]);
                float a2 = bf2f(hb[s2 * RANK + lane]);
                float a3 = bf2f(hb[s3 * RANK + lane]);
                float a4 = bf2f(hb[s4 * RANK + lane]);
                float a5 = bf2f(hb[s5 * RANK + lane]);
                float a6 = bf2f(hb[s6 * RANK + lane]);
                float a7 = bf2f(hb[s7 * RANK + lane]);
                pp *= ((a0 * a1) * (a2 * a3)) * ((a4 * a5) * (a6 * a7));
            }
            for (; j < n; ++j) {
                int s = __shfl(sidx, j);
                pp *= bf2f(hb[s * RANK + lane]);
            }
        }
        p[i] = pp * norm[node];
    }

    float4 pv;
    pv.x = p[0]; pv.y = p[1]; pv.z = p[2]; pv.w = p[3];
    pls[wave * 64 + lane] = pv;
    __syncthreads();

    // phase 2: out[base+i][j] = sum_r trans[base+i][r] * V[j][r], j = lane / lane+64
    const float4* pw = &pls[wave * 64];
    const float4* vA = (const float4*)(V + lane * RANK);          // row j = lane
    const float4* vB = (const float4*)(V + (lane + 64) * RANK);   // row j = lane+64
    float2 acc0 = {0.f, 0.f}, acc1 = {0.f, 0.f}, acc2 = {0.f, 0.f}, acc3 = {0.f, 0.f};
#pragma unroll 4
    for (int q = 0; q < RANK / 4; ++q) {
        float4 va = vA[q];
        float4 vb = vB[q];
        float4 p0 = pw[4 * q + 0];   // LDS broadcast reads
        float4 p1 = pw[4 * q + 1];
        float4 p2 = pw[4 * q + 2];
        float4 p3 = pw[4 * q + 3];
        acc0.x = fmaf(p0.x, va.x, fmaf(p1.x, va.y, fmaf(p2.x, va.z, fmaf(p3.x, va.w, acc0.x))));
        acc0.y = fmaf(p0.x, vb.x, fmaf(p1.x, vb.y, fmaf(p2.x, vb.z, fmaf(p3.x, vb.w, acc0.y))));
        acc1.x = fmaf(p0.y, va.x, fmaf(p1.y, va.y, fmaf(p2.y, va.z, fmaf(p3.y, va.w, acc1.x))));
        acc1.y = fmaf(p0.y, vb.x, fmaf(p1.y, vb.y, fmaf(p2.y, vb.z, fmaf(p3.y, vb.w, acc1.y))));
        acc2.x = fmaf(p0.z, va.x, fmaf(p1.z, va.y, fmaf(p2.z, va.z, fmaf(p3.z, va.w, acc2.x))));
        acc2.y = fmaf(p0.z, vb.x, fmaf(p1.z, vb.y, fmaf(p2.z, vb.z, fmaf(p3.z, vb.w, acc2.y))));
        acc3.x = fmaf(p0.w, va.x, fmaf(p1.w, va.y, fmaf(p2.w, va.z, fmaf(p3.w, va.w, acc3.x))));
        acc3.y = fmaf(p0.w, vb.x, fmaf(p1.w, vb.y, fmaf(p2.w, vb.z, fmaf(p3.w, vb.w, acc3.y))));
    }
    out[(base + 0) * HIDDEN + lane]      = acc0.x;
    out[(base + 0) * HIDDEN + 64 + lane] = acc0.y;
    out[(base + 1) * HIDDEN + lane]      = acc1.x;
    out[(base + 1) * HIDDEN + 64 + lane] = acc1.y;
    out[(base + 2) * HIDDEN + lane]      = acc2.x;
    out[(base + 2) * HIDDEN + 64 + lane] = acc2.y;
    out[(base + 3) * HIDDEN + lane]      = acc3.x;
    out[(base + 3) * HIDDEN + 64 + lane] = acc3.y;
}

// ---------------- launch ----------------

extern "C" void kernel_launch(void* const* d_in, const int* in_sizes, int n_in,
                              void* d_out, int out_size, void* d_ws, size_t ws_size,
                              hipStream_t stream) {
    const float* x    = (const float*)d_in[0];
    const float* norm = (const float*)d_in[1];
    const float* W    = (const float*)d_in[2];
    const float* V    = (const float*)d_in[3];
    const int*   src  = (const int*)d_in[4];
    const int*   dst  = (const int*)d_in[5];
    float* out = (float*)d_out;

    // workspace layout (ws): hb (bf16), offs, eidx, small bucket arrays
    unsigned short* hb = (unsigned short*)d_ws;              // N*RANK bf16 (12.8 MB)
    int*   offs        = (int*)(hb + (long)N_NODES * RANK);  // N+1
    int*   eidx        = offs + N_NODES + 1;                 // E
    int*   bhist       = eidx + N_EDGES;                     // NBUCK
    int*   bucket_offs = bhist + NBUCK;                      // NBUCK+1
    int*   bucket_cur  = bucket_offs + NBUCK + 1;            // NBUCK

    // scratch inside d_out (dead until agg_gemm writes out):
    unsigned* pairs    = (unsigned*)d_out;                   // E uint32 (6.4 MB)
    int*     blockhist = (int*)d_out + 2097152;              // at +8 MB: C_BLOCKS*NBUCK ints

    hipMemsetAsync(bhist, 0, NBUCK * sizeof(int), stream);
    gemm1_hist_kernel<<<GEMM1_BLOCKS + C_BLOCKS, 256, 0, stream>>>(x, W, hb, dst, bhist, blockhist);
    bucket_scan_kernel<<<1, 512, 0, stream>>>(bhist, bucket_offs, bucket_cur, offs);
    binscatter_kernel<<<C_BLOCKS, 256, 0, stream>>>(src, dst, blockhist, bucket_cur, pairs);
    bucket_build_kernel<<<NBUCK, 256, 0, stream>>>(pairs, bucket_offs, offs, eidx);
    agg_gemm_kernel<<<N_NODES / 16, 256, 0, stream>>>(hb, norm, V, offs, eidx, out);
}

// Round 7
// 308.134 us; speedup vs baseline: 1.1782x; 1.1782x over previous
//
#include <hip/hip_runtime.h>
#include <hip/hip_bf16.h>

#define N_NODES 100000
#define N_EDGES 1600000
#define IN_FEA 128
#define HIDDEN 128
#define RANK 64

#define NBUCK 391          // ceil(N_NODES/256): bucket b = nodes [b*256, b*256+256)
#define C_BLOCKS 1024
#define EPB 1563           // ceil(N_EDGES / C_BLOCKS)
#define GEMM1_BLOCKS 1563  // ceil(N_NODES / 64)

// ---------------- helpers ----------------

__device__ __forceinline__ void fma4(float4& a, float s, const float4& b) {
    a.x = fmaf(s, b.x, a.x);
    a.y = fmaf(s, b.y, a.y);
    a.z = fmaf(s, b.z, a.z);
    a.w = fmaf(s, b.w, a.w);
}

__device__ __forceinline__ unsigned short f2bf_rne(float f) {
    unsigned u = __float_as_uint(f);
    u += 0x7fffu + ((u >> 16) & 1u);
    return (unsigned short)(u >> 16);
}

__device__ __forceinline__ float bf2f(unsigned short s) {
    return __uint_as_float(((unsigned)s) << 16);
}

// ---------------- fused GEMM1 + bucket histogram ----------------
// blocks [0, GEMM1_BLOCKS): h_bf = bf16(x @ W), 64 nodes/block (4 nodes x 4 ranks / thread).
// blocks [GEMM1_BLOCKS, +C_BLOCKS): per-block bucket histogram.

__global__ __launch_bounds__(256) void gemm1_hist_kernel(const float* __restrict__ x,
                                                         const float* __restrict__ W,
                                                         unsigned short* __restrict__ hb,
                                                         const int* __restrict__ dst,
                                                         int* __restrict__ bhist,
                                                         int* __restrict__ blockhist) {
    __shared__ float Wl[IN_FEA * RANK];  // 32 KB (hist aliases first 1.6 KB)
    int t = threadIdx.x;

    if (blockIdx.x >= GEMM1_BLOCKS) {
        int* hist = (int*)Wl;
        int b = blockIdx.x - GEMM1_BLOCKS;
        for (int i = t; i < NBUCK; i += 256) hist[i] = 0;
        __syncthreads();
        int b0 = b * EPB;
        int b1 = min(b0 + EPB, N_EDGES);
        for (int e = b0 + t; e < b1; e += 256)
            atomicAdd(&hist[dst[e] >> 8], 1);
        __syncthreads();
        for (int i = t; i < NBUCK; i += 256) {
            int c = hist[i];
            blockhist[b * NBUCK + i] = c;
            if (c) atomicAdd(&bhist[i], c);
        }
        return;
    }

    for (int i = t; i < IN_FEA * RANK; i += 256) Wl[i] = W[i];
    __syncthreads();

    int r0 = (t & 15) * 4;
    int n0 = blockIdx.x * 64 + (t >> 4) * 4;
    // clamp row pointers so tail block never reads past x
    const float4* x0 = (const float4*)(x + (long)min(n0 + 0, N_NODES - 1) * IN_FEA);
    const float4* x1 = (const float4*)(x + (long)min(n0 + 1, N_NODES - 1) * IN_FEA);
    const float4* x2 = (const float4*)(x + (long)min(n0 + 2, N_NODES - 1) * IN_FEA);
    const float4* x3 = (const float4*)(x + (long)min(n0 + 3, N_NODES - 1) * IN_FEA);
    float4 a0 = {0.f, 0.f, 0.f, 0.f}, a1 = a0, a2 = a0, a3 = a0;
    for (int k4 = 0; k4 < IN_FEA / 4; ++k4) {
        float4 v0 = x0[k4], v1 = x1[k4], v2 = x2[k4], v3 = x3[k4];
        int kb = k4 * 4;
        float4 w0 = *(const float4*)&Wl[(kb + 0) * RANK + r0];
        float4 w1 = *(const float4*)&Wl[(kb + 1) * RANK + r0];
        float4 w2 = *(const float4*)&Wl[(kb + 2) * RANK + r0];
        float4 w3 = *(const float4*)&Wl[(kb + 3) * RANK + r0];
        fma4(a0, v0.x, w0); fma4(a0, v0.y, w1); fma4(a0, v0.z, w2); fma4(a0, v0.w, w3);
        fma4(a1, v1.x, w0); fma4(a1, v1.y, w1); fma4(a1, v1.z, w2); fma4(a1, v1.w, w3);
        fma4(a2, v2.x, w0); fma4(a2, v2.y, w1); fma4(a2, v2.z, w2); fma4(a2, v2.w, w3);
        fma4(a3, v3.x, w0); fma4(a3, v3.y, w1); fma4(a3, v3.z, w2); fma4(a3, v3.w, w3);
    }
    float4 accs[4] = {a0, a1, a2, a3};
#pragma unroll
    for (int i = 0; i < 4; ++i) {
        if (n0 + i < N_NODES) {
            ushort4 o;
            o.x = f2bf_rne(accs[i].x); o.y = f2bf_rne(accs[i].y);
            o.z = f2bf_rne(accs[i].z); o.w = f2bf_rne(accs[i].w);
            *(ushort4*)(hb + (n0 + i) * RANK + r0) = o;
        }
    }
}

// ---------------- CSR build (rest) ----------------

__global__ void bucket_scan_kernel(const int* __restrict__ bhist,
                                   int* __restrict__ bucket_offs,
                                   int* __restrict__ bucket_cursor,
                                   int* __restrict__ offs) {
    __shared__ int sd[512];
    int t = threadIdx.x;
    int v = (t < NBUCK) ? bhist[t] : 0;
    sd[t] = v;
    __syncthreads();
    for (int off = 1; off < 512; off <<= 1) {
        int a = 0;
        if (t >= off) a = sd[t - off];
        __syncthreads();
        sd[t] += a;
        __syncthreads();
    }
    if (t < NBUCK) {
        int excl = sd[t] - v;
        bucket_offs[t] = excl;
        bucket_cursor[t] = excl;
    }
    if (t == 0) {
        bucket_offs[NBUCK] = N_EDGES;
        offs[N_NODES] = N_EDGES;
    }
}

__global__ __launch_bounds__(256) void binscatter_kernel(const int* __restrict__ src,
                                                         const int* __restrict__ dst,
                                                         const int* __restrict__ blockhist,
                                                         int* __restrict__ bucket_cursor,
                                                         unsigned* __restrict__ pairs) {
    __shared__ int wbase[NBUCK];
    __shared__ int cur[NBUCK];
    int t = threadIdx.x;
    for (int i = t; i < NBUCK; i += 256) {
        int c = blockhist[blockIdx.x * NBUCK + i];
        wbase[i] = c ? atomicAdd(&bucket_cursor[i], c) : 0;
        cur[i] = 0;
    }
    __syncthreads();
    int b0 = blockIdx.x * EPB;
    int b1 = min(b0 + EPB, N_EDGES);
    for (int e = b0 + t; e < b1; e += 256) {
        int d = dst[e];
        int s = src[e];
        int bk = d >> 8;
        int lp = atomicAdd(&cur[bk], 1);
        pairs[wbase[bk] + lp] = ((unsigned)s << 8) | (unsigned)(d & 255);
    }
}

__global__ __launch_bounds__(256) void bucket_build_kernel(const unsigned* __restrict__ pairs,
                                                           const int* __restrict__ bucket_offs,
                                                           int* __restrict__ offs,
                                                           int* __restrict__ eidx) {
    __shared__ int dcnt[256];
    __shared__ int sd[256];
    __shared__ int cur[256];
    int b = blockIdx.x, t = threadIdx.x;
    int base = bucket_offs[b], end = bucket_offs[b + 1];
    dcnt[t] = 0;
    __syncthreads();
    for (int i = base + t; i < end; i += 256)
        atomicAdd(&dcnt[pairs[i] & 255u], 1);
    __syncthreads();
    int v = dcnt[t];
    sd[t] = v;
    __syncthreads();
    for (int off = 1; off < 256; off <<= 1) {
        int a = 0;
        if (t >= off) a = sd[t - off];
        __syncthreads();
        sd[t] += a;
        __syncthreads();
    }
    int excl = sd[t] - v;
    int node = b * 256 + t;
    if (node < N_NODES) offs[node] = base + excl;
    cur[t] = excl;
    __syncthreads();
    for (int i = base + t; i < end; i += 256) {
        unsigned r = pairs[i];
        int lp = atomicAdd(&cur[r & 255u], 1);
        eidx[base + lp] = (int)(r >> 8);
    }
}

// ---------------- fused aggregation + GEMM2 ----------------
// One node per wave (R4's winning gather shape), grid 25000 x 4 waves.
// Phase 1: lane = rank, bf16 h gather (128 B/row).
// Phase 2: V in fp16 LDS (16.9 KB, stride-66 pad), trans via 1 KB LDS broadcast;
// each wave computes its own node's 128-wide out row (j = lane, lane+64).

__global__ __launch_bounds__(256) void agg_gemm_kernel(const unsigned short* __restrict__ hb,
                                                       const float* __restrict__ norm,
                                                       const float* __restrict__ V,
                                                       const int* __restrict__ offs,
                                                       const int* __restrict__ eidx,
                                                       float* __restrict__ out) {
    __shared__ _Float16 VLh[HIDDEN * 66];   // 16,896 B
    __shared__ float pls[4][64];            // 1 KB
    int t = threadIdx.x;
    for (int idx = t; idx < HIDDEN * RANK; idx += 256)
        VLh[(idx >> 6) * 66 + (idx & 63)] = (_Float16)V[idx];

    int wave = t >> 6, lane = t & 63;
    int node = blockIdx.x * 4 + wave;
    int beg = offs[node], end = offs[node + 1];
    float p = 1.0f;
    for (int c = beg; c < end; c += 64) {
        int n = min(64, end - c);
        int sidx = (c + lane < end) ? eidx[c + lane] : 0;
        int j = 0;
        for (; j + 8 <= n; j += 8) {
            int s0 = __shfl(sidx, j + 0);
            int s1 = __shfl(sidx, j + 1);
            int s2 = __shfl(sidx, j + 2);
            int s3 = __shfl(sidx, j + 3);
            int s4 = __shfl(sidx, j + 4);
            int s5 = __shfl(sidx, j + 5);
            int s6 = __shfl(sidx, j + 6);
            int s7 = __shfl(sidx, j + 7);
            float a0 = bf2f(hb[s0 * RANK + lane]);
            float a1 = bf2f(hb[s1 * RANK + lane]);
            float a2 = bf2f(hb[s2 * RANK + lane]);
            float a3 = bf2f(hb[s3 * RANK + lane]);
            float a4 = bf2f(hb[s4 * RANK + lane]);
            float a5 = bf2f(hb[s5 * RANK + lane]);
            float a6 = bf2f(hb[s6 * RANK + lane]);
            float a7 = bf2f(hb[s7 * RANK + lane]);
            p *= ((a0 * a1) * (a2 * a3)) * ((a4 * a5) * (a6 * a7));
        }
        for (; j + 4 <= n; j += 4) {
            int s0 = __shfl(sidx, j + 0);
            int s1 = __shfl(sidx, j + 1);
            int s2 = __shfl(sidx, j + 2);
            int s3 = __shfl(sidx, j + 3);
            float a0 = bf2f(hb[s0 * RANK + lane]);
            float a1 = bf2f(hb[s1 * RANK + lane]);
            float a2 = bf2f(hb[s2 * RANK + lane]);
            float a3 = bf2f(hb[s3 * RANK + lane]);
            p *= (a0 * a1) * (a2 * a3);
        }
        for (; j < n; ++j) {
            int s = __shfl(sidx, j);
            p *= bf2f(hb[s * RANK + lane]);
        }
    }
    pls[wave][lane] = p * norm[node];
    __syncthreads();   // covers V staging + pls visibility

    const float4* pw = (const float4*)pls[wave];
    const _Float16* rA = &VLh[lane * 66];
    const _Float16* rB = &VLh[(lane + 64) * 66];
    float accA = 0.f, accB = 0.f;
#pragma unroll
    for (int q = 0; q < RANK / 4; ++q) {
        float4 pp = pw[q];                  // b128 broadcast
        float a0 = (float)rA[4 * q + 0], a1 = (float)rA[4 * q + 1];
        float a2 = (float)rA[4 * q + 2], a3 = (float)rA[4 * q + 3];
        float b0 = (float)rB[4 * q + 0], b1 = (float)rB[4 * q + 1];
        float b2 = (float)rB[4 * q + 2], b3 = (float)rB[4 * q + 3];
        accA = fmaf(pp.x, a0, fmaf(pp.y, a1, fmaf(pp.z, a2, fmaf(pp.w, a3, accA))));
        accB = fmaf(pp.x, b0, fmaf(pp.y, b1, fmaf(pp.z, b2, fmaf(pp.w, b3, accB))));
    }
    out[node * HIDDEN + lane]      = accA;
    out[node * HIDDEN + 64 + lane] = accB;
}

// ---------------- launch ----------------

extern "C" void kernel_launch(void* const* d_in, const int* in_sizes, int n_in,
                              void* d_out, int out_size, void* d_ws, size_t ws_size,
                              hipStream_t stream) {
    const float* x    = (const float*)d_in[0];
    const float* norm = (const float*)d_in[1];
    const float* W    = (const float*)d_in[2];
    const float* V    = (const float*)d_in[3];
    const int*   src  = (const int*)d_in[4];
    const int*   dst  = (const int*)d_in[5];
    float* out = (float*)d_out;

    // workspace layout (ws): hb (bf16), offs, eidx, small bucket arrays
    unsigned short* hb = (unsigned short*)d_ws;              // N*RANK bf16 (12.8 MB)
    int*   offs        = (int*)(hb + (long)N_NODES * RANK);  // N+1
    int*   eidx        = offs + N_NODES + 1;                 // E
    int*   bhist       = eidx + N_EDGES;                     // NBUCK
    int*   bucket_offs = bhist + NBUCK;                      // NBUCK+1
    int*   bucket_cur  = bucket_offs + NBUCK + 1;            // NBUCK

    // scratch inside d_out (dead until agg_gemm writes out):
    unsigned* pairs    = (unsigned*)d_out;                   // E uint32 (6.4 MB)
    int*     blockhist = (int*)d_out + 2097152;              // at +8 MB: C_BLOCKS*NBUCK ints

    hipMemsetAsync(bhist, 0, NBUCK * sizeof(int), stream);
    gemm1_hist_kernel<<<GEMM1_BLOCKS + C_BLOCKS, 256, 0, stream>>>(x, W, hb, dst, bhist, blockhist);
    bucket_scan_kernel<<<1, 512, 0, stream>>>(bhist, bucket_offs, bucket_cur, offs);
    binscatter_kernel<<<C_BLOCKS, 256, 0, stream>>>(src, dst, blockhist, bucket_cur, pairs);
    bucket_build_kernel<<<NBUCK, 256, 0, stream>>>(pairs, bucket_offs, offs, eidx);
    agg_gemm_kernel<<<N_NODES / 4, 256, 0, stream>>>(hb, norm, V, offs, eidx, out);
}